// Round 5
// baseline (122.068 us; speedup 1.0000x reference)
//
#include <hip/hip_runtime.h>
#include <math.h>

// ---------------------------------------------------------------------------
// Exp-domain tree machine, round 5: single fused kernel.
//  - no precompute dispatch: each thread (= tree node) builds its ey row and
//    folded recurrence consts {A1,B1,C0,D,E} in registers from sw/dw/cw;
//    vw sigmoids staged straight to LDS.
//  - phase 3 uses mx = 0 (attn <= ~35, exp cannot overflow; underflow
//    harmless) -> no 5-step max shuffle chain.
//  - BPB 8, grid 1024 (25 KB LDS/block) for more blocks/CU.
// ---------------------------------------------------------------------------

#define TINY 1.8600378e-44f   // exp(-BOUND - lc - LOG2)

struct WPtrs {
  const float* sw[8];
  const float* dw[8];
  const float* cw[8];
  const float* vw;
};

__device__ __forceinline__ float sigmoidf_(float x) {
  return 1.0f / (1.0f + __expf(-x));
}

__global__ __launch_bounds__(256) void tm_all(
    const float* __restrict__ x0, WPtrs p, float* __restrict__ out) {
  __shared__ float  ex0s[128];        // 8 rows x 16 : exp(x0)
  __shared__ float2 a_lds[8 * 256];   // [b][node] = (a1, a2), log domain
  __shared__ float4 evt_s[512];       // [i][k] : v0(k, d=4i..4i+3)

  const int t  = threadIdx.x;
  const int b0 = blockIdx.x * 8;

  // stage exp(x0) for 8 batch rows
  if (t < 128) ex0s[t] = __expf(x0[b0 * 16 + t]);

  // stage value sigmoids (v1 = 1 - v0, reconstructed at use)
  {
    const float4* vw4 = (const float4*)p.vw;   // vw: (2, 256, 8)
    float4 u0 = vw4[t * 2],       u1 = vw4[t * 2 + 1];
    float4 w0 = vw4[512 + t * 2], w1 = vw4[512 + t * 2 + 1];
    evt_s[t] = make_float4(sigmoidf_(u0.x - w0.x), sigmoidf_(u0.y - w0.y),
                           sigmoidf_(u0.z - w0.z), sigmoidf_(u0.w - w0.w));
    evt_s[256 + t] = make_float4(sigmoidf_(u1.x - w1.x), sigmoidf_(u1.y - w1.y),
                                 sigmoidf_(u1.z - w1.z), sigmoidf_(u1.w - w1.w));
  }

  // per-node tables in registers (thread = node)
  float ey_[4][16];                   // ey_[s][a]
  float4 q[4];                        // {A1, B1, C0, D} per s
  float  E[4];
  if (t < 255) {
    const int depth = 31 - __clz(t + 1);
    const int tloc  = t - ((1 << depth) - 1);
    const int nS    = (1 << depth) * 4;
    const float4* sw0 = (const float4*)p.sw[depth] + tloc * 4;        // 4 rows x 4 bits
    const float4* sw1 = (const float4*)(p.sw[depth] + nS * 4) + tloc * 4;
    const float* dwp = p.dw[depth];
    const float* cwp = p.cw[depth];
    float d0a[4], d1a[4], c0a[4], c1a[4];
    *(float4*)d0a = *(const float4*)(dwp + tloc * 4);
    *(float4*)d1a = *(const float4*)(dwp + nS + tloc * 4);
    *(float4*)c0a = *(const float4*)(cwp + tloc * 4);
    *(float4*)c1a = *(const float4*)(cwp + nS + tloc * 4);
#pragma unroll
    for (int s = 0; s < 4; s++) {
      float4 a0 = sw0[s], a1 = sw1[s];
      float pk0 = sigmoidf_(a0.x - a1.x);
      float pk1 = sigmoidf_(a0.y - a1.y);
      float pk2 = sigmoidf_(a0.z - a1.z);
      float pk3 = sigmoidf_(a0.w - a1.w);
      float r2[2]  = {1.0f - pk0, pk0};        // k=0 is MSB of a
      float r4[4], r8[8];
#pragma unroll
      for (int i = 0; i < 2; i++) {
        r4[i * 2]     = r2[i] * (1.0f - pk1);
        r4[i * 2 + 1] = r2[i] * pk1;
      }
#pragma unroll
      for (int i = 0; i < 4; i++) {
        r8[i * 2]     = r4[i] * (1.0f - pk2);
        r8[i * 2 + 1] = r4[i] * pk2;
      }
#pragma unroll
      for (int i = 0; i < 8; i++) {
        ey_[s][i * 2]     = r8[i] * (1.0f - pk3);
        ey_[s][i * 2 + 1] = r8[i] * pk3;
      }
      // fold dw/cw into recurrence constants
      float ed0 = sigmoidf_(d0a[s] - d1a[s]);
      float ed1 = 1.0f - ed0;
      float W0  = sigmoidf_(c0a[s] - c1a[s]);
      float W1  = 1.0f - W0;
      float A   = ed0 - ed1;                   // X10 = A*P0 + ed1
      float C   = 2.0f * ed0;                  // X11 = C*(1-P0)
      q[s] = make_float4(A * W1, ed1 * W1, C * W0, fmaf(A, W0, -C * W1));
      E[s] = fmaf(C, W1, ed1 * W0);
    }
  }
  __syncthreads();

  // phase 2: loop over batch rows in pairs; ex broadcast from LDS
  if (t < 255) {
    const float4* exv = (const float4*)ex0s;
#pragma unroll
    for (int b = 0; b < 8; b += 2) {
      float eA[16], eB[16];
#pragma unroll
      for (int i = 0; i < 4; i++) {
        ((float4*)eA)[i] = exv[b * 4 + i];
        ((float4*)eB)[i] = exv[b * 4 + 4 + i];
      }
      float PA[4] = {0, 0, 0, 0}, PB[4] = {0, 0, 0, 0};
#pragma unroll
      for (int a = 0; a < 16; a++) {
        PA[0] = fmaf(ey_[0][a], eA[a], PA[0]);  PB[0] = fmaf(ey_[0][a], eB[a], PB[0]);
        PA[1] = fmaf(ey_[1][a], eA[a], PA[1]);  PB[1] = fmaf(ey_[1][a], eB[a], PB[1]);
        PA[2] = fmaf(ey_[2][a], eA[a], PA[2]);  PB[2] = fmaf(ey_[2][a], eB[a], PB[2]);
        PA[3] = fmaf(ey_[3][a], eA[a], PA[3]);  PB[3] = fmaf(ey_[3][a], eB[a], PB[3]);
      }
      float S1a = TINY, S2a = 1.0f, S3a = TINY;
      float S1b = TINY, S2b = 1.0f, S3b = TINY;
#pragma unroll
      for (int s = 0; s < 4; s++) {
        {
          float pp = PA[s];
          S1a = fmaf(S2a, fmaf(q[s].x, pp, q[s].y), S1a);   // += S2*X10*W1
          S3a = fmaf(S2a, fmaf(-q[s].z, pp, q[s].z), S3a);  // += S2*X11*W0
          S2a *= fmaf(q[s].w, pp, E[s]);                    // *= X10*W0+X11*W1
        }
        {
          float pp = PB[s];
          S1b = fmaf(S2b, fmaf(q[s].x, pp, q[s].y), S1b);
          S3b = fmaf(S2b, fmaf(-q[s].z, pp, q[s].z), S3b);
          S2b *= fmaf(q[s].w, pp, E[s]);
        }
      }
      a_lds[b * 256 + t]       = make_float2(__logf(S1a + S2a), __logf(S3a));
      a_lds[(b + 1) * 256 + t] = make_float2(__logf(S1b + S2b), __logf(S3b));
    }
  }
  __syncthreads();

  // phase 3: 8 groups of 32 lanes, group g -> batch row g. mx = 0.
  const int g     = t >> 5;
  const int chunk = t & 31;
  const float2* arow = a_lds + g * 256;

  // depths 0..4: r-invariant (k = chunk + 32r keeps bits 0..4)
  float base = 0.f;
#pragma unroll
  for (int i2 = 0; i2 < 5; i2++) {
    int node = ((1 << i2) - 1) + (chunk & ((1 << i2) - 1));
    float2 v = arow[node];
    base += ((chunk >> i2) & 1) ? v.y : v.x;
  }
  float2 A5  = arow[31 + chunk];
  float2 A6a = arow[63 + chunk];
  float2 A6b = arow[95 + chunk];
  float2 A7[4];
#pragma unroll
  for (int j = 0; j < 4; j++) A7[j] = arow[127 + chunk + 32 * j];

  float acc[8] = {0, 0, 0, 0, 0, 0, 0, 0};
  float Stot = 0.f;
#pragma unroll
  for (int r = 0; r < 8; r++) {
    float t5 = (r & 1) ? A5.y : A5.x;
    float2 a6 = (r & 1) ? A6b : A6a;
    float t6 = ((r >> 1) & 1) ? a6.y : a6.x;
    float2 a7 = A7[r & 3];
    float t7 = (r >> 2) ? a7.y : a7.x;
    float e = __expf(base + t5 + t6 + t7);     // mx = 0: attn <= ~35, safe
    Stot += e;
    int k = chunk + 32 * r;
    float4 v0 = evt_s[k];
    float4 v1 = evt_s[256 + k];
    acc[0] = fmaf(e, v0.x, acc[0]);  acc[1] = fmaf(e, v0.y, acc[1]);
    acc[2] = fmaf(e, v0.z, acc[2]);  acc[3] = fmaf(e, v0.w, acc[3]);
    acc[4] = fmaf(e, v1.x, acc[4]);  acc[5] = fmaf(e, v1.y, acc[5]);
    acc[6] = fmaf(e, v1.z, acc[6]);  acc[7] = fmaf(e, v1.w, acc[7]);
  }

  // value-halving butterfly: 8 accs -> 1 per lane (d = bitrev3(chunk)),
  // then full sums over lane bits 3,4. Stot reduces in a parallel chain.
#define VH_STEP(OFF, HALF)                                          \
  {                                                                 \
    const bool hi = (chunk & (OFF)) != 0;                           \
    _Pragma("unroll")                                               \
    for (int qq = 0; qq < (HALF); qq++) {                           \
      float send = hi ? acc[qq] : acc[qq + (HALF)];                 \
      float got  = __shfl_xor(send, (OFF), 64);                     \
      acc[qq] = (hi ? acc[qq + (HALF)] : acc[qq]) + got;            \
    }                                                               \
  }
  VH_STEP(1, 4)
  VH_STEP(2, 2)
  VH_STEP(4, 1)
#undef VH_STEP
  float a0 = acc[0];
  a0 += __shfl_xor(a0, 8, 64);
  a0 += __shfl_xor(a0, 16, 64);
#pragma unroll
  for (int off = 1; off < 32; off <<= 1)
    Stot += __shfl_xor(Stot, off, 64);

  const int d = ((chunk & 1) << 2) | (chunk & 2) | ((chunk >> 2) & 1);
  const int b = b0 + g;
  if (chunk < 8)
    out[b * 8 + d] = __logf(a0);                       // y0
  else if (chunk < 16)
    out[65536 + b * 8 + d] = __logf(Stot - a0);        // y1 (v1 = 1 - v0)
}

extern "C" void kernel_launch(void* const* d_in, const int* in_sizes, int n_in,
                              void* d_out, int out_size, void* d_ws, size_t ws_size,
                              hipStream_t stream) {
  WPtrs p;
  const float* x0 = (const float*)d_in[0];
  if (in_sizes[3] == 8) {        // interleaved dict order sw0,dw0,cw0,sw1,...
    for (int i = 0; i < 8; i++) {
      p.sw[i] = (const float*)d_in[2 + 3 * i];
      p.dw[i] = (const float*)d_in[3 + 3 * i];
      p.cw[i] = (const float*)d_in[4 + 3 * i];
    }
  } else {                       // grouped signature order
    for (int i = 0; i < 8; i++) {
      p.sw[i] = (const float*)d_in[2 + i];
      p.dw[i] = (const float*)d_in[10 + i];
      p.cw[i] = (const float*)d_in[18 + i];
    }
  }
  p.vw = (const float*)d_in[26];

  tm_all<<<1024, 256, 0, stream>>>(x0, p, (float*)d_out);
}

// Round 6
// 115.927 us; speedup vs baseline: 1.0530x; 1.0530x over previous
//
#include <hip/hip_runtime.h>
#include <math.h>

// ---------------------------------------------------------------------------
// Exp-domain tree machine, round 6 = round-4 structure (two kernels,
// thread = node, tables amortized in ws) + round-5's validated mx=0
// simplification in phase 3 (attn <= ~35 -> exp cannot overflow; the
// serial 5-hop max shuffle chain is deleted).
// ---------------------------------------------------------------------------

// workspace layout (float offsets)
#define NWS_EYT  0        // ey_t[16][1020] : ey transposed [a][j]
#define NWS_Q4   16320    // q4[4][256][4]  : per (s,node): {A1,B1,C0,D}
#define NWS_E1   20416    // e1[4][256]     : per (s,node): E
#define NWS_EVT  21440    // evt[2][256][4] : v0(k, d=4i+c) at [i][k][c]
// total 23488 floats = 93952 B

#define TINY 1.8600378e-44f   // exp(-BOUND - lc - LOG2)

struct WPtrs {
  const float* sw[8];
  const float* dw[8];
  const float* cw[8];
  const float* vw;
};

__device__ __forceinline__ float sigmoidf_(float x) {
  return 1.0f / (1.0f + __expf(-x));
}

__global__ void tm_precompute(WPtrs p, float* __restrict__ ws) {
  int tid = blockIdx.x * blockDim.x + threadIdx.x;
  if (tid < 1020) {
    int jg = tid;
    int v = (jg >> 2) + 1;
    int depth = 31 - __clz(v);
    int nS = (1 << depth) * 4;                 // rows (n*SHUF) at this depth
    int jl = jg - 4 * ((1 << depth) - 1);      // local row within depth
    const float* sw = p.sw[depth];             // (2, nS, 4)
    float p0[4];
#pragma unroll
    for (int k = 0; k < 4; k++)
      p0[k] = sigmoidf_(sw[jl * 4 + k] - sw[nS * 4 + jl * 4 + k]);
#pragma unroll
    for (int a = 0; a < 16; a++) {
      float prod = 1.0f;
#pragma unroll
      for (int k = 0; k < 4; k++) {
        int bit = (a >> (3 - k)) & 1;          // k=0 is MSB
        prod *= bit ? p0[k] : (1.0f - p0[k]);
      }
      ws[NWS_EYT + a * 1020 + jg] = prod;      // transposed [a][j]
    }
    // fold dw/cw into recurrence constants
    const float* dw = p.dw[depth];             // (2, nS)
    float ed0 = sigmoidf_(dw[jl] - dw[nS + jl]);
    float ed1 = 1.0f - ed0;
    const float* cw = p.cw[depth];             // (2, 1, n, 4) flat (2, nS)
    float W0 = sigmoidf_(cw[jl] - cw[nS + jl]);
    float W1 = 1.0f - W0;
    float A  = ed0 - ed1;                      // X10 = A*P0 + ed1
    float C  = 2.0f * ed0;                     // X11 = C*(1-P0)
    float A1 = A * W1, B1 = ed1 * W1;
    float A0 = A * W0, B0 = ed1 * W0;
    float C0 = C * W0, C1 = C * W1;
    float D  = A0 - C1;                        // X10*W0 + X11*W1 = D*P0 + E
    float E  = B0 + C1;
    int ng = jg >> 2, s = jg & 3;
    float* q = ws + NWS_Q4 + (s * 256 + ng) * 4;
    q[0] = A1; q[1] = B1; q[2] = C0; q[3] = D;
    ws[NWS_E1 + s * 256 + ng] = E;
  } else if (tid >= 1024 && tid < 3072) {
    int e = tid - 1024;                        // e = k*8 + d
    int k = e >> 3, d = e & 7;
    float v0 = sigmoidf_(p.vw[e] - p.vw[2048 + e]);
    ws[NWS_EVT + ((d >> 2) * 256 + k) * 4 + (d & 3)] = v0;
  }
}

// 16 batch rows per block of 256 threads; thread = tree node (255 active)
// in phase 2, 32-lane branch groups in phase 3.
__global__ __launch_bounds__(256) void tm_main(
    const float* __restrict__ x0,
    const float* __restrict__ ws, float* __restrict__ out) {
  __shared__ float  ex0s[256];        // [b][a] 16x16 exp(x0)
  __shared__ float2 a_lds[16 * 256];  // [b][node] = (a1, a2), log domain
  __shared__ float4 evt_s[512];       // [i][k] : v0(k, 4i..4i+3)

  const int t  = threadIdx.x;
  const int b0 = blockIdx.x * 16;

  // stage exp(x0) for this block's 16 batch rows
  ex0s[t] = __expf(x0[b0 * 16 + t]);
  {
    const float4* evt_g = (const float4*)(ws + NWS_EVT);
    evt_s[t]       = evt_g[t];
    evt_s[t + 256] = evt_g[t + 256];
  }

  // per-node tables -> registers (once per block)
  float4 ey[16];
  float4 q[4];
  float  E[4];
  {
    const int node = (t < 255) ? t : 0;
    const float4* eyt4 = (const float4*)(ws + NWS_EYT);
    const float4* q4   = (const float4*)(ws + NWS_Q4);
    const float*  e1   = ws + NWS_E1;
#pragma unroll
    for (int a = 0; a < 16; a++) ey[a] = eyt4[a * 255 + node];
#pragma unroll
    for (int s = 0; s < 4; s++) { q[s] = q4[s * 256 + node]; E[s] = e1[s * 256 + node]; }
  }
  __syncthreads();

  // phase 2: loop over batch rows in pairs, ex broadcast from LDS,
  // pipelined one pair ahead.
  if (t < 255) {
    const float4* exv = (const float4*)ex0s;
    float4 cxa[4], cxb[4], nxa[4], nxb[4];
#pragma unroll
    for (int i = 0; i < 4; i++) { cxa[i] = exv[i]; cxb[i] = exv[4 + i]; }
#pragma unroll
    for (int b = 0; b < 16; b += 2) {
      if (b + 2 < 16) {
#pragma unroll
        for (int i = 0; i < 4; i++) {
          nxa[i] = exv[(b + 2) * 4 + i];
          nxb[i] = exv[(b + 3) * 4 + i];
        }
      }
      float eA[16], eB[16];
#pragma unroll
      for (int i = 0; i < 4; i++) {
        ((float4*)eA)[i] = cxa[i];
        ((float4*)eB)[i] = cxb[i];
      }
      float PA[4] = {0, 0, 0, 0}, PB[4] = {0, 0, 0, 0};
#pragma unroll
      for (int a = 0; a < 16; a++) {
        PA[0] = fmaf(ey[a].x, eA[a], PA[0]);  PB[0] = fmaf(ey[a].x, eB[a], PB[0]);
        PA[1] = fmaf(ey[a].y, eA[a], PA[1]);  PB[1] = fmaf(ey[a].y, eB[a], PB[1]);
        PA[2] = fmaf(ey[a].z, eA[a], PA[2]);  PB[2] = fmaf(ey[a].z, eB[a], PB[2]);
        PA[3] = fmaf(ey[a].w, eA[a], PA[3]);  PB[3] = fmaf(ey[a].w, eB[a], PB[3]);
      }
      float S1a = TINY, S2a = 1.0f, S3a = TINY;
      float S1b = TINY, S2b = 1.0f, S3b = TINY;
#pragma unroll
      for (int s = 0; s < 4; s++) {
        {
          float pp = PA[s];
          S1a = fmaf(S2a, fmaf(q[s].x, pp, q[s].y), S1a);   // += S2*X10*W1
          S3a = fmaf(S2a, fmaf(-q[s].z, pp, q[s].z), S3a);  // += S2*X11*W0
          S2a *= fmaf(q[s].w, pp, E[s]);                    // *= X10*W0+X11*W1
        }
        {
          float pp = PB[s];
          S1b = fmaf(S2b, fmaf(q[s].x, pp, q[s].y), S1b);
          S3b = fmaf(S2b, fmaf(-q[s].z, pp, q[s].z), S3b);
          S2b *= fmaf(q[s].w, pp, E[s]);
        }
      }
      a_lds[b * 256 + t]       = make_float2(__logf(S1a + S2a), __logf(S3a));
      a_lds[(b + 1) * 256 + t] = make_float2(__logf(S1b + S2b), __logf(S3b));
#pragma unroll
      for (int i = 0; i < 4; i++) { cxa[i] = nxa[i]; cxb[i] = nxb[i]; }
    }
  }
  __syncthreads();

  // phase 3: 8 groups of 32 lanes; group g handles rows g and g+8. mx = 0
  // (attn <= ~35, exp cannot overflow; underflow harmless after final log —
  // validated on bench inputs in round 5).
  const int g     = t >> 5;
  const int chunk = t & 31;
#pragma unroll
  for (int rr = 0; rr < 2; rr++) {
    const int row = g + 8 * rr;
    const float2* arow = a_lds + row * 256;

    // depths 0..4: r-invariant (k = chunk + 32r keeps bits 0..4)
    float base = 0.f;
#pragma unroll
    for (int i2 = 0; i2 < 5; i2++) {
      int node = ((1 << i2) - 1) + (chunk & ((1 << i2) - 1));
      float2 v = arow[node];
      base += ((chunk >> i2) & 1) ? v.y : v.x;
    }
    // depth 5: node fixed, ch = r&1 ; depth 6: 2 nodes, ch=(r>>1)&1 ;
    // depth 7: 4 nodes, ch = r>>2
    float2 A5  = arow[31 + chunk];
    float2 A6a = arow[63 + chunk];
    float2 A6b = arow[95 + chunk];
    float2 A7[4];
#pragma unroll
    for (int j = 0; j < 4; j++) A7[j] = arow[127 + chunk + 32 * j];

    float acc[8] = {0, 0, 0, 0, 0, 0, 0, 0};
    float Stot = 0.f;
#pragma unroll
    for (int r = 0; r < 8; r++) {
      float t5 = (r & 1) ? A5.y : A5.x;
      float2 a6 = (r & 1) ? A6b : A6a;
      float t6 = ((r >> 1) & 1) ? a6.y : a6.x;
      float2 a7 = A7[r & 3];
      float t7 = (r >> 2) ? a7.y : a7.x;
      float e = __expf(base + t5 + t6 + t7);
      Stot += e;
      int k = chunk + 32 * r;
      float4 v0 = evt_s[k];
      float4 v1 = evt_s[256 + k];
      acc[0] = fmaf(e, v0.x, acc[0]);  acc[1] = fmaf(e, v0.y, acc[1]);
      acc[2] = fmaf(e, v0.z, acc[2]);  acc[3] = fmaf(e, v0.w, acc[3]);
      acc[4] = fmaf(e, v1.x, acc[4]);  acc[5] = fmaf(e, v1.y, acc[5]);
      acc[6] = fmaf(e, v1.z, acc[6]);  acc[7] = fmaf(e, v1.w, acc[7]);
    }

    // value-halving butterfly: 8 accs -> 1 per lane (d = bitrev3(chunk)),
    // then full sums over remaining lane bits.
#define VH_STEP(OFF, HALF)                                          \
    {                                                               \
      const bool hi = (chunk & (OFF)) != 0;                         \
      _Pragma("unroll")                                             \
      for (int qq = 0; qq < (HALF); qq++) {                         \
        float send = hi ? acc[qq] : acc[qq + (HALF)];               \
        float got  = __shfl_xor(send, (OFF), 64);                   \
        acc[qq] = (hi ? acc[qq + (HALF)] : acc[qq]) + got;          \
      }                                                             \
    }
    VH_STEP(1, 4)
    VH_STEP(2, 2)
    VH_STEP(4, 1)
#undef VH_STEP
    float a0 = acc[0];
    a0 += __shfl_xor(a0, 8, 64);
    a0 += __shfl_xor(a0, 16, 64);
#pragma unroll
    for (int off = 1; off < 32; off <<= 1)
      Stot += __shfl_xor(Stot, off, 64);

    const int d = ((chunk & 1) << 2) | (chunk & 2) | ((chunk >> 2) & 1);
    const int b = b0 + row;
    if (chunk < 8)
      out[b * 8 + d] = __logf(a0);                       // y0
    else if (chunk < 16)
      out[65536 + b * 8 + d] = __logf(Stot - a0);        // y1 (v1 = 1 - v0)
  }
}

extern "C" void kernel_launch(void* const* d_in, const int* in_sizes, int n_in,
                              void* d_out, int out_size, void* d_ws, size_t ws_size,
                              hipStream_t stream) {
  WPtrs p;
  const float* x0 = (const float*)d_in[0];
  if (in_sizes[3] == 8) {        // interleaved dict order sw0,dw0,cw0,sw1,...
    for (int i = 0; i < 8; i++) {
      p.sw[i] = (const float*)d_in[2 + 3 * i];
      p.dw[i] = (const float*)d_in[3 + 3 * i];
      p.cw[i] = (const float*)d_in[4 + 3 * i];
    }
  } else {                       // grouped signature order
    for (int i = 0; i < 8; i++) {
      p.sw[i] = (const float*)d_in[2 + i];
      p.dw[i] = (const float*)d_in[10 + i];
      p.cw[i] = (const float*)d_in[18 + i];
    }
  }
  p.vw = (const float*)d_in[26];

  float* ws = (float*)d_ws;
  tm_precompute<<<12, 256, 0, stream>>>(p, ws);
  tm_main<<<512, 256, 0, stream>>>(x0, ws, (float*)d_out);
}

// Round 7
// 114.403 us; speedup vs baseline: 1.0670x; 1.0133x over previous
//
#include <hip/hip_runtime.h>
#include <math.h>

// ---------------------------------------------------------------------------
// Exp-domain tree machine, round 7:
//  - fully linear-domain phase 2/3: a-values stored as (S1+S2, S3) directly
//    (no logf); phase-3 branch weight = PRODUCT of 8 a-terms (no expf).
//    exp(sum of logs) == product. Only the 16 output logs remain.
//  - BPB 8, grid 1024: LDS 26 KB/block -> 4 blocks/CU, 4 waves/SIMD for
//    latency hiding of the fmaf chains (R6 had 2).
//  - R4 two-kernel structure (tables amortized via 12-block precompute).
// ---------------------------------------------------------------------------

// workspace layout (float offsets)
#define NWS_EYT  0        // ey_t[16][1020] : ey transposed [a][j]
#define NWS_Q4   16320    // q4[4][256][4]  : per (s,node): {A1,B1,C0,D}
#define NWS_E1   20416    // e1[4][256]     : per (s,node): E
#define NWS_EVT  21440    // evt[2][256][4] : v0(k, d=4i+c) at [i][k][c]
// total 23488 floats = 93952 B

#define TINY 1.8600378e-44f   // exp(-BOUND - lc - LOG2)

struct WPtrs {
  const float* sw[8];
  const float* dw[8];
  const float* cw[8];
  const float* vw;
};

__device__ __forceinline__ float sigmoidf_(float x) {
  return 1.0f / (1.0f + __expf(-x));
}

__global__ void tm_precompute(WPtrs p, float* __restrict__ ws) {
  int tid = blockIdx.x * blockDim.x + threadIdx.x;
  if (tid < 1020) {
    int jg = tid;
    int v = (jg >> 2) + 1;
    int depth = 31 - __clz(v);
    int nS = (1 << depth) * 4;                 // rows (n*SHUF) at this depth
    int jl = jg - 4 * ((1 << depth) - 1);      // local row within depth
    const float* sw = p.sw[depth];             // (2, nS, 4)
    float p0[4];
#pragma unroll
    for (int k = 0; k < 4; k++)
      p0[k] = sigmoidf_(sw[jl * 4 + k] - sw[nS * 4 + jl * 4 + k]);
#pragma unroll
    for (int a = 0; a < 16; a++) {
      float prod = 1.0f;
#pragma unroll
      for (int k = 0; k < 4; k++) {
        int bit = (a >> (3 - k)) & 1;          // k=0 is MSB
        prod *= bit ? p0[k] : (1.0f - p0[k]);
      }
      ws[NWS_EYT + a * 1020 + jg] = prod;      // transposed [a][j]
    }
    // fold dw/cw into recurrence constants
    const float* dw = p.dw[depth];             // (2, nS)
    float ed0 = sigmoidf_(dw[jl] - dw[nS + jl]);
    float ed1 = 1.0f - ed0;
    const float* cw = p.cw[depth];             // (2, 1, n, 4) flat (2, nS)
    float W0 = sigmoidf_(cw[jl] - cw[nS + jl]);
    float W1 = 1.0f - W0;
    float A  = ed0 - ed1;                      // X10 = A*P0 + ed1
    float C  = 2.0f * ed0;                     // X11 = C*(1-P0)
    float A1 = A * W1, B1 = ed1 * W1;
    float A0 = A * W0, B0 = ed1 * W0;
    float C0 = C * W0, C1 = C * W1;
    float D  = A0 - C1;                        // X10*W0 + X11*W1 = D*P0 + E
    float E  = B0 + C1;
    int ng = jg >> 2, s = jg & 3;
    float* q = ws + NWS_Q4 + (s * 256 + ng) * 4;
    q[0] = A1; q[1] = B1; q[2] = C0; q[3] = D;
    ws[NWS_E1 + s * 256 + ng] = E;
  } else if (tid >= 1024 && tid < 3072) {
    int e = tid - 1024;                        // e = k*8 + d
    int k = e >> 3, d = e & 7;
    float v0 = sigmoidf_(p.vw[e] - p.vw[2048 + e]);
    ws[NWS_EVT + ((d >> 2) * 256 + k) * 4 + (d & 3)] = v0;
  }
}

// 8 batch rows per block of 256 threads; thread = tree node (255 active)
// in phase 2, 32-lane branch groups in phase 3.
__global__ __launch_bounds__(256) void tm_main(
    const float* __restrict__ x0,
    const float* __restrict__ ws, float* __restrict__ out) {
  __shared__ float  ex0s[128];        // [b][a] 8x16 exp(x0)
  __shared__ float2 a_lds[8 * 256];   // [b][node] = (a1, a2), LINEAR domain
  __shared__ float4 evt_s[512];       // [i][k] : v0(k, 4i..4i+3)

  const int t  = threadIdx.x;
  const int b0 = blockIdx.x * 8;

  // stage exp(x0) for this block's 8 batch rows + value table
  if (t < 128) ex0s[t] = __expf(x0[b0 * 16 + t]);
  {
    const float4* evt_g = (const float4*)(ws + NWS_EVT);
    evt_s[t]       = evt_g[t];
    evt_s[t + 256] = evt_g[t + 256];
  }

  // per-node tables -> registers (once per block)
  float4 ey[16];
  float4 q[4];
  float  E[4];
  {
    const int node = (t < 255) ? t : 0;
    const float4* eyt4 = (const float4*)(ws + NWS_EYT);
    const float4* q4   = (const float4*)(ws + NWS_Q4);
    const float*  e1   = ws + NWS_E1;
#pragma unroll
    for (int a = 0; a < 16; a++) ey[a] = eyt4[a * 255 + node];
#pragma unroll
    for (int s = 0; s < 4; s++) { q[s] = q4[s * 256 + node]; E[s] = e1[s * 256 + node]; }
  }
  __syncthreads();

  // phase 2: loop over batch rows in pairs; ex broadcast from LDS.
  // a-values stored in LINEAR domain (no logf).
  if (t < 255) {
    const float4* exv = (const float4*)ex0s;
#pragma unroll
    for (int b = 0; b < 8; b += 2) {
      float eA[16], eB[16];
#pragma unroll
      for (int i = 0; i < 4; i++) {
        ((float4*)eA)[i] = exv[b * 4 + i];
        ((float4*)eB)[i] = exv[b * 4 + 4 + i];
      }
      float PA[4] = {0, 0, 0, 0}, PB[4] = {0, 0, 0, 0};
#pragma unroll
      for (int a = 0; a < 16; a++) {
        PA[0] = fmaf(ey[a].x, eA[a], PA[0]);  PB[0] = fmaf(ey[a].x, eB[a], PB[0]);
        PA[1] = fmaf(ey[a].y, eA[a], PA[1]);  PB[1] = fmaf(ey[a].y, eB[a], PB[1]);
        PA[2] = fmaf(ey[a].z, eA[a], PA[2]);  PB[2] = fmaf(ey[a].z, eB[a], PB[2]);
        PA[3] = fmaf(ey[a].w, eA[a], PA[3]);  PB[3] = fmaf(ey[a].w, eB[a], PB[3]);
      }
      float S1a = TINY, S2a = 1.0f, S3a = TINY;
      float S1b = TINY, S2b = 1.0f, S3b = TINY;
#pragma unroll
      for (int s = 0; s < 4; s++) {
        {
          float pp = PA[s];
          S1a = fmaf(S2a, fmaf(q[s].x, pp, q[s].y), S1a);   // += S2*X10*W1
          S3a = fmaf(S2a, fmaf(-q[s].z, pp, q[s].z), S3a);  // += S2*X11*W0
          S2a *= fmaf(q[s].w, pp, E[s]);                    // *= X10*W0+X11*W1
        }
        {
          float pp = PB[s];
          S1b = fmaf(S2b, fmaf(q[s].x, pp, q[s].y), S1b);
          S3b = fmaf(S2b, fmaf(-q[s].z, pp, q[s].z), S3b);
          S2b *= fmaf(q[s].w, pp, E[s]);
        }
      }
      a_lds[b * 256 + t]       = make_float2(S1a + S2a, S3a);
      a_lds[(b + 1) * 256 + t] = make_float2(S1b + S2b, S3b);
    }
  }
  __syncthreads();

  // phase 3: 8 groups of 32 lanes, group g -> batch row g.
  // branch weight e = PRODUCT of the 8 selected linear a-terms
  // (== exp(sum of logs); flush-to-zero matches validated expf behavior).
  const int g     = t >> 5;
  const int chunk = t & 31;
  const float2* arow = a_lds + g * 256;

  // depths 0..4: r-invariant (k = chunk + 32r keeps bits 0..4)
  float base = 1.0f;
#pragma unroll
  for (int i2 = 0; i2 < 5; i2++) {
    int node = ((1 << i2) - 1) + (chunk & ((1 << i2) - 1));
    float2 v = arow[node];
    base *= ((chunk >> i2) & 1) ? v.y : v.x;
  }
  // depth 5: node fixed, ch = r&1 ; depth 6: 2 nodes, ch=(r>>1)&1 ;
  // depth 7: 4 nodes, ch = r>>2
  float2 A5  = arow[31 + chunk];
  float2 A6a = arow[63 + chunk];
  float2 A6b = arow[95 + chunk];
  float2 A7[4];
#pragma unroll
  for (int j = 0; j < 4; j++) A7[j] = arow[127 + chunk + 32 * j];

  float acc[8] = {0, 0, 0, 0, 0, 0, 0, 0};
  float Stot = 0.f;
#pragma unroll
  for (int r = 0; r < 8; r++) {
    float t5 = (r & 1) ? A5.y : A5.x;
    float2 a6 = (r & 1) ? A6b : A6a;
    float t6 = ((r >> 1) & 1) ? a6.y : a6.x;
    float2 a7 = A7[r & 3];
    float t7 = (r >> 2) ? a7.y : a7.x;
    float e = base * t5 * t6 * t7;
    Stot += e;
    int k = chunk + 32 * r;
    float4 v0 = evt_s[k];
    float4 v1 = evt_s[256 + k];
    acc[0] = fmaf(e, v0.x, acc[0]);  acc[1] = fmaf(e, v0.y, acc[1]);
    acc[2] = fmaf(e, v0.z, acc[2]);  acc[3] = fmaf(e, v0.w, acc[3]);
    acc[4] = fmaf(e, v1.x, acc[4]);  acc[5] = fmaf(e, v1.y, acc[5]);
    acc[6] = fmaf(e, v1.z, acc[6]);  acc[7] = fmaf(e, v1.w, acc[7]);
  }

  // value-halving butterfly: 8 accs -> 1 per lane (d = bitrev3(chunk)),
  // then full sums over remaining lane bits. Stot reduces in parallel.
#define VH_STEP(OFF, HALF)                                          \
  {                                                                 \
    const bool hi = (chunk & (OFF)) != 0;                           \
    _Pragma("unroll")                                               \
    for (int qq = 0; qq < (HALF); qq++) {                           \
      float send = hi ? acc[qq] : acc[qq + (HALF)];                 \
      float got  = __shfl_xor(send, (OFF), 64);                     \
      acc[qq] = (hi ? acc[qq + (HALF)] : acc[qq]) + got;            \
    }                                                               \
  }
  VH_STEP(1, 4)
  VH_STEP(2, 2)
  VH_STEP(4, 1)
#undef VH_STEP
  float a0 = acc[0];
  a0 += __shfl_xor(a0, 8, 64);
  a0 += __shfl_xor(a0, 16, 64);
#pragma unroll
  for (int off = 1; off < 32; off <<= 1)
    Stot += __shfl_xor(Stot, off, 64);

  const int d = ((chunk & 1) << 2) | (chunk & 2) | ((chunk >> 2) & 1);
  const int b = b0 + g;
  if (chunk < 8)
    out[b * 8 + d] = __logf(a0);                       // y0
  else if (chunk < 16)
    out[65536 + b * 8 + d] = __logf(Stot - a0);        // y1 (v1 = 1 - v0)
}

extern "C" void kernel_launch(void* const* d_in, const int* in_sizes, int n_in,
                              void* d_out, int out_size, void* d_ws, size_t ws_size,
                              hipStream_t stream) {
  WPtrs p;
  const float* x0 = (const float*)d_in[0];
  if (in_sizes[3] == 8) {        // interleaved dict order sw0,dw0,cw0,sw1,...
    for (int i = 0; i < 8; i++) {
      p.sw[i] = (const float*)d_in[2 + 3 * i];
      p.dw[i] = (const float*)d_in[3 + 3 * i];
      p.cw[i] = (const float*)d_in[4 + 3 * i];
    }
  } else {                       // grouped signature order
    for (int i = 0; i < 8; i++) {
      p.sw[i] = (const float*)d_in[2 + i];
      p.dw[i] = (const float*)d_in[10 + i];
      p.cw[i] = (const float*)d_in[18 + i];
    }
  }
  p.vw = (const float*)d_in[26];

  float* ws = (float*)d_ws;
  tm_precompute<<<12, 256, 0, stream>>>(p, ws);
  tm_main<<<1024, 256, 0, stream>>>(x0, ws, (float*)d_out);
}

// Round 9
// 111.744 us; speedup vs baseline: 1.0924x; 1.0238x over previous
//
#include <hip/hip_runtime.h>
#include <math.h>

// ---------------------------------------------------------------------------
// Exp-domain tree machine, round 9 = round-8 intent, compile-fixed:
// v_pk_fma_f32 (2 FMA/instr) via an inline fma2() on float2 ext-vectors
// (macro version broke on braced-init commas). Phase-2 dots packed over
// s-pairs, recurrence packed over the (A,B) batch pair, phase-3 value
// accumulation packed over d-pairs. Math identical to R7.
// ---------------------------------------------------------------------------

typedef float v2f __attribute__((ext_vector_type(2)));

__device__ __forceinline__ v2f splat2(float x) { return (v2f){x, x}; }
__device__ __forceinline__ v2f fma2(v2f a, v2f b, v2f c) {
  return __builtin_elementwise_fma(a, b, c);
}
__device__ __forceinline__ v2f mk2(float x, float y) { return (v2f){x, y}; }

// workspace layout (float offsets)
#define NWS_EYT  0        // ey_t[16][1020] : ey transposed [a][j]
#define NWS_Q4   16320    // q4[4][256][4]  : per (s,node): {A1,B1,C0,D}
#define NWS_E1   20416    // e1[4][256]     : per (s,node): E
#define NWS_EVT  21440    // evt[2][256][4] : v0(k, d=4i+c) at [i][k][c]
// total 23488 floats = 93952 B

#define TINY 1.8600378e-44f   // exp(-BOUND - lc - LOG2)

struct WPtrs {
  const float* sw[8];
  const float* dw[8];
  const float* cw[8];
  const float* vw;
};

__device__ __forceinline__ float sigmoidf_(float x) {
  return 1.0f / (1.0f + __expf(-x));
}

__global__ void tm_precompute(WPtrs p, float* __restrict__ ws) {
  int tid = blockIdx.x * blockDim.x + threadIdx.x;
  if (tid < 1020) {
    int jg = tid;
    int v = (jg >> 2) + 1;
    int depth = 31 - __clz(v);
    int nS = (1 << depth) * 4;                 // rows (n*SHUF) at this depth
    int jl = jg - 4 * ((1 << depth) - 1);      // local row within depth
    const float* sw = p.sw[depth];             // (2, nS, 4)
    float p0[4];
#pragma unroll
    for (int k = 0; k < 4; k++)
      p0[k] = sigmoidf_(sw[jl * 4 + k] - sw[nS * 4 + jl * 4 + k]);
#pragma unroll
    for (int a = 0; a < 16; a++) {
      float prod = 1.0f;
#pragma unroll
      for (int k = 0; k < 4; k++) {
        int bit = (a >> (3 - k)) & 1;          // k=0 is MSB
        prod *= bit ? p0[k] : (1.0f - p0[k]);
      }
      ws[NWS_EYT + a * 1020 + jg] = prod;      // transposed [a][j]
    }
    // fold dw/cw into recurrence constants
    const float* dw = p.dw[depth];             // (2, nS)
    float ed0 = sigmoidf_(dw[jl] - dw[nS + jl]);
    float ed1 = 1.0f - ed0;
    const float* cw = p.cw[depth];             // (2, 1, n, 4) flat (2, nS)
    float W0 = sigmoidf_(cw[jl] - cw[nS + jl]);
    float W1 = 1.0f - W0;
    float A  = ed0 - ed1;                      // X10 = A*P0 + ed1
    float C  = 2.0f * ed0;                     // X11 = C*(1-P0)
    float A1 = A * W1, B1 = ed1 * W1;
    float A0 = A * W0, B0 = ed1 * W0;
    float C0 = C * W0, C1 = C * W1;
    float D  = A0 - C1;                        // X10*W0 + X11*W1 = D*P0 + E
    float E  = B0 + C1;
    int ng = jg >> 2, s = jg & 3;
    float* q = ws + NWS_Q4 + (s * 256 + ng) * 4;
    q[0] = A1; q[1] = B1; q[2] = C0; q[3] = D;
    ws[NWS_E1 + s * 256 + ng] = E;
  } else if (tid >= 1024 && tid < 3072) {
    int e = tid - 1024;                        // e = k*8 + d
    int k = e >> 3, d = e & 7;
    float v0 = sigmoidf_(p.vw[e] - p.vw[2048 + e]);
    ws[NWS_EVT + ((d >> 2) * 256 + k) * 4 + (d & 3)] = v0;
  }
}

// 8 batch rows per block of 256 threads; thread = tree node (255 active)
// in phase 2, 32-lane branch groups in phase 3.
__global__ __launch_bounds__(256) void tm_main(
    const float* __restrict__ x0,
    const float* __restrict__ ws, float* __restrict__ out) {
  __shared__ float  ex0s[128];        // [b][a] 8x16 exp(x0)
  __shared__ float2 a_lds[8 * 256];   // [b][node] = (a1, a2), LINEAR domain
  __shared__ float4 evt_s[512];       // [i][k] : v0(k, 4i..4i+3)

  const int t  = threadIdx.x;
  const int b0 = blockIdx.x * 8;

  // stage exp(x0) for this block's 8 batch rows + value table
  if (t < 128) ex0s[t] = __expf(x0[b0 * 16 + t]);
  {
    const float4* evt_g = (const float4*)(ws + NWS_EVT);
    evt_s[t]       = evt_g[t];
    evt_s[t + 256] = evt_g[t + 256];
  }

  // per-node tables -> registers (once per block), ey split into pk pairs
  v2f eyxy[16], eyzw[16];
  float4 q[4];
  float  E[4];
  {
    const int node = (t < 255) ? t : 0;
    const float4* eyt4 = (const float4*)(ws + NWS_EYT);
    const float4* q4   = (const float4*)(ws + NWS_Q4);
    const float*  e1   = ws + NWS_E1;
#pragma unroll
    for (int a = 0; a < 16; a++) {
      float4 w = eyt4[a * 255 + node];
      eyxy[a] = mk2(w.x, w.y);
      eyzw[a] = mk2(w.z, w.w);
    }
#pragma unroll
    for (int s = 0; s < 4; s++) { q[s] = q4[s * 256 + node]; E[s] = e1[s * 256 + node]; }
  }
  __syncthreads();

  // phase 2: batch rows in pairs; dots packed over s-pairs, recurrence
  // packed over the (A,B) batch pair. All pk-fma.
  if (t < 255) {
    const float4* exv = (const float4*)ex0s;
#pragma unroll
    for (int b = 0; b < 8; b += 2) {
      float eA[16], eB[16];
#pragma unroll
      for (int i = 0; i < 4; i++) {
        ((float4*)eA)[i] = exv[b * 4 + i];
        ((float4*)eB)[i] = exv[b * 4 + 4 + i];
      }
      v2f P01A = splat2(0.f), P23A = splat2(0.f);
      v2f P01B = splat2(0.f), P23B = splat2(0.f);
#pragma unroll
      for (int a = 0; a < 16; a++) {
        v2f sA = splat2(eA[a]), sB = splat2(eB[a]);
        P01A = fma2(eyxy[a], sA, P01A);  P23A = fma2(eyzw[a], sA, P23A);
        P01B = fma2(eyxy[a], sB, P01B);  P23B = fma2(eyzw[a], sB, P23B);
      }
      const float PA[4] = {P01A.x, P01A.y, P23A.x, P23A.y};
      const float PB[4] = {P01B.x, P01B.y, P23B.x, P23B.y};
      v2f S1 = splat2(TINY), S2 = splat2(1.0f), S3 = splat2(TINY);
#pragma unroll
      for (int s = 0; s < 4; s++) {
        v2f pp = mk2(PA[s], PB[s]);
        v2f qx = splat2(q[s].x), qy = splat2(q[s].y);
        v2f qz = splat2(q[s].z), qw = splat2(q[s].w);
        S1 = fma2(S2, fma2(qx, pp, qy), S1);     // += S2*X10*W1
        S3 = fma2(S2, fma2(-qz, pp, qz), S3);    // += S2*X11*W0
        S2 = S2 * fma2(qw, pp, splat2(E[s]));    // *= X10*W0+X11*W1
      }
      a_lds[b * 256 + t]       = make_float2(S1.x + S2.x, S3.x);
      a_lds[(b + 1) * 256 + t] = make_float2(S1.y + S2.y, S3.y);
    }
  }
  __syncthreads();

  // phase 3: 8 groups of 32 lanes, group g -> batch row g.
  // branch weight e = PRODUCT of the 8 selected linear a-terms.
  const int g     = t >> 5;
  const int chunk = t & 31;
  const float2* arow = a_lds + g * 256;

  // depths 0..4: r-invariant (k = chunk + 32r keeps bits 0..4)
  float base = 1.0f;
#pragma unroll
  for (int i2 = 0; i2 < 5; i2++) {
    int node = ((1 << i2) - 1) + (chunk & ((1 << i2) - 1));
    float2 v = arow[node];
    base *= ((chunk >> i2) & 1) ? v.y : v.x;
  }
  float2 A5  = arow[31 + chunk];
  float2 A6a = arow[63 + chunk];
  float2 A6b = arow[95 + chunk];
  float2 A7[4];
#pragma unroll
  for (int j = 0; j < 4; j++) A7[j] = arow[127 + chunk + 32 * j];

  v2f a01 = splat2(0.f), a23 = splat2(0.f), a45 = splat2(0.f), a67 = splat2(0.f);
  float Stot = 0.f;
#pragma unroll
  for (int r = 0; r < 8; r++) {
    float t5 = (r & 1) ? A5.y : A5.x;
    float2 a6 = (r & 1) ? A6b : A6a;
    float t6 = ((r >> 1) & 1) ? a6.y : a6.x;
    float2 a7 = A7[r & 3];
    float t7 = (r >> 2) ? a7.y : a7.x;
    float e = base * t5 * t6 * t7;
    Stot += e;
    int k = chunk + 32 * r;
    float4 v0 = evt_s[k];
    float4 v1 = evt_s[256 + k];
    v2f es = splat2(e);
    v2f v0a = mk2(v0.x, v0.y), v0b = mk2(v0.z, v0.w);
    v2f v1a = mk2(v1.x, v1.y), v1b = mk2(v1.z, v1.w);
    a01 = fma2(es, v0a, a01);
    a23 = fma2(es, v0b, a23);
    a45 = fma2(es, v1a, a45);
    a67 = fma2(es, v1b, a67);
  }

  float acc[8] = {a01.x, a01.y, a23.x, a23.y, a45.x, a45.y, a67.x, a67.y};

  // value-halving butterfly: 8 accs -> 1 per lane (d = bitrev3(chunk)),
  // then full sums over remaining lane bits. Stot reduces in parallel.
#define VH_STEP(OFF, HALF)                                          \
  {                                                                 \
    const bool hi = (chunk & (OFF)) != 0;                           \
    _Pragma("unroll")                                               \
    for (int qq = 0; qq < (HALF); qq++) {                           \
      float send = hi ? acc[qq] : acc[qq + (HALF)];                 \
      float got  = __shfl_xor(send, (OFF), 64);                     \
      acc[qq] = (hi ? acc[qq + (HALF)] : acc[qq]) + got;            \
    }                                                               \
  }
  VH_STEP(1, 4)
  VH_STEP(2, 2)
  VH_STEP(4, 1)
#undef VH_STEP
  float a0 = acc[0];
  a0 += __shfl_xor(a0, 8, 64);
  a0 += __shfl_xor(a0, 16, 64);
#pragma unroll
  for (int off = 1; off < 32; off <<= 1)
    Stot += __shfl_xor(Stot, off, 64);

  const int d = ((chunk & 1) << 2) | (chunk & 2) | ((chunk >> 2) & 1);
  const int b = b0 + g;
  if (chunk < 8)
    out[b * 8 + d] = __logf(a0);                       // y0
  else if (chunk < 16)
    out[65536 + b * 8 + d] = __logf(Stot - a0);        // y1 (v1 = 1 - v0)
}

extern "C" void kernel_launch(void* const* d_in, const int* in_sizes, int n_in,
                              void* d_out, int out_size, void* d_ws, size_t ws_size,
                              hipStream_t stream) {
  WPtrs p;
  const float* x0 = (const float*)d_in[0];
  if (in_sizes[3] == 8) {        // interleaved dict order sw0,dw0,cw0,sw1,...
    for (int i = 0; i < 8; i++) {
      p.sw[i] = (const float*)d_in[2 + 3 * i];
      p.dw[i] = (const float*)d_in[3 + 3 * i];
      p.cw[i] = (const float*)d_in[4 + 3 * i];
    }
  } else {                       // grouped signature order
    for (int i = 0; i < 8; i++) {
      p.sw[i] = (const float*)d_in[2 + i];
      p.dw[i] = (const float*)d_in[10 + i];
      p.cw[i] = (const float*)d_in[18 + i];
    }
  }
  p.vw = (const float*)d_in[26];

  float* ws = (float*)d_ws;
  tm_precompute<<<12, 256, 0, stream>>>(p, ws);
  tm_main<<<1024, 256, 0, stream>>>(x0, ws, (float*)d_out);
}